// Round 9
// baseline (250.030 us; speedup 1.0000x reference)
//
#include <hip/hip_runtime.h>
#include <math.h>

#define B_SZ   2
#define T_SEQ  2048
#define NH     16
#define HDIM   64
#define D_MOD  1024
#define DL     512
#define DC     256
#define MROWS  4096   // B*T

typedef __attribute__((ext_vector_type(8))) short bf16x8;
typedef __attribute__((ext_vector_type(4))) float f32x4;

#define SCALE_Q 0.18033688011112042f   // (1/sqrt(64)) * log2(e)
#define PSTR 68    // Ps stride: 4-row quad offset = 8 banks mod 32 -> conflict-free b16 writes

static __device__ __forceinline__ unsigned short f2bf(float f) {
    union { float f; unsigned u; } v; v.f = f;
    unsigned r = v.u + 0x7fffu + ((v.u >> 16) & 1u);   // RNE
    return (unsigned short)(r >> 16);
}

// async global->LDS, 16B per lane; lds base wave-uniform, lane i -> base+i*16.
static __device__ __forceinline__ void gl_lds16(const unsigned short* g,
                                                unsigned short* l) {
    __builtin_amdgcn_global_load_lds(
        (const __attribute__((address_space(1))) unsigned int*)g,
        (__attribute__((address_space(3))) unsigned int*)l, 16, 0, 0);
}

// ---------------------------------------------------------------------------
// Convert x + 6 weights fp32 -> bf16, and build RoPE table [T,32] (cos,sin).
// ---------------------------------------------------------------------------
__global__ __launch_bounds__(256) void cvt_bf16(
    const float* __restrict__ x,  const float* __restrict__ wq,
    const float* __restrict__ wkvl, const float* __restrict__ wcomp,
    const float* __restrict__ wexp, const float* __restrict__ wfkv,
    const float* __restrict__ wout,
    unsigned short* __restrict__ xb,  unsigned short* __restrict__ wqh,
    unsigned short* __restrict__ wkvlh, unsigned short* __restrict__ wcomph,
    unsigned short* __restrict__ wexph, unsigned short* __restrict__ wfkvh,
    unsigned short* __restrict__ wouth, float2* __restrict__ rope_tab)
{
    const int g = blockIdx.x * 256 + threadIdx.x;
    const int stride = gridDim.x * 256;
#define CVT_SEG(src, dst, n4)                                              \
    for (int i = g; i < (n4); i += stride) {                               \
        float4 v = ((const float4*)(src))[i];                              \
        unsigned short h[4] = {f2bf(v.x), f2bf(v.y), f2bf(v.z), f2bf(v.w)};\
        *(uint2*)((dst) + (size_t)i * 4) = *(uint2*)h;                     \
    }
    CVT_SEG(x, xb, 1048576)
    CVT_SEG(wq, wqh, 262144)
    CVT_SEG(wkvl, wkvlh, 131072)
    CVT_SEG(wcomp, wcomph, 32768)
    CVT_SEG(wexp, wexph, 32768)
    CVT_SEG(wfkv, wfkvh, 262144)
    CVT_SEG(wout, wouth, 262144)
#undef CVT_SEG
    for (int i = g; i < T_SEQ * 32; i += stride) {
        const int t = i >> 5, fi = i & 31;
        const float inv = __expf((float)fi * (-9.210340371976184f / 32.0f));
        float sn, cs; sincosf((float)t * inv, &sn, &cs);
        rope_tab[i] = make_float2(cs, sn);
    }
}

// ===========================================================================
// 64x64-tile bf16 MFMA GEMM, row-split waves: wave w owns rows w*16..w*16+15
// x ALL 64 cols -> RoPE col^32 pairing stays in-wave. BK=32.
// ===========================================================================
#define GEMM64R_PROLOG(Aptr, Wptr, Kdim)                                       \
    __shared__ unsigned short As[64 * 32];                                     \
    __shared__ unsigned short Ws[64 * 32];                                     \
    const int tid = threadIdx.x;                                               \
    const int w = tid >> 6, lane = tid & 63;                                   \
    const int l16 = lane & 15, quad = lane >> 4;                               \
    const int srow = lane >> 2, scol = (lane & 3) << 3;                        \
    const unsigned short* Ag = (Aptr) + (size_t)(m0 + w * 16 + srow) * (Kdim) + scol; \
    const unsigned short* Wg = (Wptr) + (size_t)(n0 + w * 16 + srow) * (Kdim) + scol; \
    unsigned short* Al = &As[w * 512];                                         \
    unsigned short* Wl = &Ws[w * 512];                                         \
    f32x4 acc[4];                                                              \
    _Pragma("unroll") for (int j = 0; j < 4; ++j)                              \
        acc[j] = (f32x4){0.f, 0.f, 0.f, 0.f};                                  \
    for (int k0 = 0; k0 < (Kdim); k0 += 32) {                                  \
        __syncthreads();                                                       \
        gl_lds16(Ag + k0, Al);                                                 \
        gl_lds16(Wg + k0, Wl);                                                 \
        __syncthreads();                                                       \
        const bf16x8 af = *(const bf16x8*)&As[(w * 16 + l16) * 32 + quad * 8]; \
        bf16x8 bfr[4];                                                         \
        _Pragma("unroll") for (int j = 0; j < 4; ++j)                          \
            bfr[j] = *(const bf16x8*)&Ws[(j * 16 + l16) * 32 + quad * 8];      \
        _Pragma("unroll") for (int j = 0; j < 4; ++j)                          \
            acc[j] = __builtin_amdgcn_mfma_f32_16x16x32_bf16(af, bfr[j], acc[j], 0, 0, 0); \
    }

// ---------------------------------------------------------------------------
// Combined Q-projection (+RoPE+scale) and XT (softplus) GEMM. grid (64, 24).
// ---------------------------------------------------------------------------
__global__ __launch_bounds__(256) void gemm_qxt(
    const unsigned short* __restrict__ A, const unsigned short* __restrict__ Wq,
    const unsigned short* __restrict__ Wkvl,
    const float* __restrict__ b_q, const float* __restrict__ b_kvl,
    const float* __restrict__ ts_scale, const float* __restrict__ ts_shift,
    const float2* __restrict__ tab,
    unsigned short* __restrict__ qh, unsigned short* __restrict__ xt)
{
    const int m0 = blockIdx.x * 64;
    const bool is_q = (blockIdx.y < 16);
    const int n0 = is_q ? blockIdx.y * 64 : (blockIdx.y - 16) * 64;
    const unsigned short* W = is_q ? Wq : Wkvl;

    GEMM64R_PROLOG(A, W, D_MOD)

    if (is_q) {
#pragma unroll
        for (int j = 0; j < 4; ++j) {
            const int col = n0 + j * 16 + l16;
            const int h = col >> 6, hd = col & 63;
            const float bv = b_q[col];
            const float bvp = b_q[col ^ 32];
            const float sgn = (hd < 32) ? -1.f : 1.f;
#pragma unroll
            for (int reg = 0; reg < 4; ++reg) {
                const int row = m0 + w * 16 + quad * 4 + reg;
                const int b = row >> 11, t = row & (T_SEQ - 1);
                const float2 cssn = tab[t * 32 + (hd & 31)];
                const float v  = acc[j][reg] + bv;
                const float vp = acc[j ^ 2][reg] + bvp;
                const float r = (v * cssn.x + sgn * vp * cssn.y) * SCALE_Q;
                qh[(((size_t)b * NH + h) * T_SEQ + t) * HDIM + hd] = f2bf(r);
            }
        }
    } else {
#pragma unroll
        for (int j = 0; j < 4; ++j) {
            const int col = n0 + j * 16 + l16;
            const float bv = b_kvl[col];
            const float sp_s = log1pf(expf(ts_scale[col]));
            const float sp_t = ts_shift[col];
#pragma unroll
            for (int reg = 0; reg < 4; ++reg) {
                const int row = m0 + w * 16 + quad * 4 + reg;
                const float val = (acc[j][reg] + bv) * sp_s + sp_t;
                xt[(size_t)row * DL + col] = f2bf(val);
            }
        }
    }
}

// ---------------------------------------------------------------------------
// KV decompress GEMM with fused K-RoPE and V-transpose. grid (64, 32).
// ---------------------------------------------------------------------------
__global__ __launch_bounds__(256) void gemm_kv(
    const unsigned short* __restrict__ A, const unsigned short* __restrict__ W,
    const float* __restrict__ bias, const float2* __restrict__ tab,
    unsigned short* __restrict__ kh, unsigned short* __restrict__ vth)
{
    const int m0 = blockIdx.x * 64, n0 = blockIdx.y * 64;

    GEMM64R_PROLOG(A, W, DL)

    if (n0 < 1024) {
        // K path: bias + RoPE -> kh [B*H, T, 64]
#pragma unroll
        for (int j = 0; j < 4; ++j) {
            const int col = n0 + j * 16 + l16;
            const int h = (col >> 6) & 15, hd = col & 63;
            const float bv = bias[col];
            const float bvp = bias[col ^ 32];
            const float sgn = (hd < 32) ? -1.f : 1.f;
#pragma unroll
            for (int reg = 0; reg < 4; ++reg) {
                const int row = m0 + w * 16 + quad * 4 + reg;
                const int b = row >> 11, t = row & (T_SEQ - 1);
                const float2 cssn = tab[t * 32 + (hd & 31)];
                const float v  = acc[j][reg] + bv;
                const float vp = acc[j ^ 2][reg] + bvp;
                const float r = v * cssn.x + sgn * vp * cssn.y;
                kh[(((size_t)b * NH + h) * T_SEQ + t) * HDIM + hd] = f2bf(r);
            }
        }
    } else {
        // V path: bias, transpose -> vth [B*H, 64, T] (packed 8B stores).
#pragma unroll
        for (int j = 0; j < 4; ++j) {
            const int col = n0 + j * 16 + l16;
            const int cv = col - 1024;
            const int h = cv >> 6, hd = cv & 63;
            const float bv = bias[col];
            unsigned short hv[4];
            const int r0 = m0 + w * 16 + quad * 4;
            const int b = r0 >> 11, t0 = r0 & (T_SEQ - 1);
#pragma unroll
            for (int reg = 0; reg < 4; ++reg)
                hv[reg] = f2bf(acc[j][reg] + bv);
            *(uint2*)&vth[(((size_t)b * NH + h) * HDIM + hd) * T_SEQ + t0] =
                *(uint2*)hv;
        }
    }
}

// ---------------------------------------------------------------------------
// Output GEMM: out[M,1024] fp32. grid (64, 16).
// ---------------------------------------------------------------------------
__global__ __launch_bounds__(256) void gemm_out(
    const unsigned short* __restrict__ A, const unsigned short* __restrict__ W,
    const float* __restrict__ bias, float* __restrict__ C)
{
    const int m0 = blockIdx.x * 64, n0 = blockIdx.y * 64;

    GEMM64R_PROLOG(A, W, D_MOD)

#pragma unroll
    for (int j = 0; j < 4; ++j) {
        const int col = n0 + j * 16 + l16;
        const float bv = bias[col];
#pragma unroll
        for (int reg = 0; reg < 4; ++reg) {
            const int row = m0 + w * 16 + quad * 4 + reg;
            C[(size_t)row * D_MOD + col] = acc[j][reg] + bv;
        }
    }
}

// ---------------------------------------------------------------------------
// Fused C-GEMM + LayerNorm + expand-GEMM. Block = 16 rows. 256 blocks.
// Stage 1: c[16,256] = xt @ W_comp^T (full LN row in-block), LN in regs.
// Stage 2: LN'd strip -> LDS (stride 260: conflict-free b16 writes), then
// dec[16,512] = c_ln @ W_exp^T with B-fragments streamed directly from
// global (W_exp = 256 KB, L2-hot; 64 MB aggregate ~ 2 us fabric).
// Kills the separate B kernel + the 16 MB cbh HBM round-trip.
// ---------------------------------------------------------------------------
__global__ __launch_bounds__(256) void gemm_cb(
    const unsigned short* __restrict__ A, const unsigned short* __restrict__ Wc,
    const unsigned short* __restrict__ We,
    const float* __restrict__ g, const float* __restrict__ bta,
    unsigned short* __restrict__ dec)
{
    __shared__ unsigned short As[16 * 32];
    __shared__ unsigned short Ws[256 * 32];
    __shared__ unsigned short Cs[16 * 260];
    __shared__ float redS[4][16];
    __shared__ float redQ[4][16];

    const int tid = threadIdx.x;
    const int w = tid >> 6, lane = tid & 63;
    const int l16 = lane & 15, quad = lane >> 4;
    const int m0 = blockIdx.x * 16;

    const int srow = lane >> 2, scol = (lane & 3) << 3;
    const unsigned short* Ag = A + (size_t)(m0 + srow) * DL + scol;
    const unsigned short* Wg = Wc + (size_t)(w * 64 + srow) * DL + scol;

    f32x4 acc[4];
#pragma unroll
    for (int j = 0; j < 4; ++j) acc[j] = (f32x4){0.f, 0.f, 0.f, 0.f};

    for (int k0 = 0; k0 < DL; k0 += 32) {
        __syncthreads();
        if (w == 0) gl_lds16(Ag + k0, &As[0]);
#pragma unroll
        for (int c = 0; c < 4; ++c)
            gl_lds16(Wg + (size_t)(c * 16) * DL + k0, &Ws[(w * 64 + c * 16) * 32]);
        __syncthreads();

        const bf16x8 af = *(const bf16x8*)&As[l16 * 32 + quad * 8];
        bf16x8 bfr[4];
#pragma unroll
        for (int j = 0; j < 4; ++j)
            bfr[j] = *(const bf16x8*)&Ws[(w * 64 + j * 16 + l16) * 32 + quad * 8];
#pragma unroll
        for (int j = 0; j < 4; ++j)
            acc[j] = __builtin_amdgcn_mfma_f32_16x16x32_bf16(af, bfr[j], acc[j], 0, 0, 0);
    }

    // LN reduction: per-row partials over this wave's 64 cols
    float s[4], q2[4];
#pragma unroll
    for (int reg = 0; reg < 4; ++reg) {
        float sv = (acc[0][reg] + acc[1][reg]) + (acc[2][reg] + acc[3][reg]);
        float qv = (acc[0][reg] * acc[0][reg] + acc[1][reg] * acc[1][reg]) +
                   (acc[2][reg] * acc[2][reg] + acc[3][reg] * acc[3][reg]);
#pragma unroll
        for (int off = 1; off < 16; off <<= 1) {
            sv += __shfl_xor(sv, off);
            qv += __shfl_xor(qv, off);
        }
        s[reg] = sv; q2[reg] = qv;
    }
    if (l16 == 0) {
#pragma unroll
        for (int reg = 0; reg < 4; ++reg) {
            redS[w][quad * 4 + reg] = s[reg];
            redQ[w][quad * 4 + reg] = q2[reg];
        }
    }
    __syncthreads();

#pragma unroll
    for (int reg = 0; reg < 4; ++reg) {
        const int r = quad * 4 + reg;
        const float sum = (redS[0][r] + redS[1][r]) + (redS[2][r] + redS[3][r]);
        const float sq  = (redQ[0][r] + redQ[1][r]) + (redQ[2][r] + redQ[3][r]);
        const float mu  = sum * (1.0f / DC);
        const float var = sq * (1.0f / DC) - mu * mu;
        const float rstd = rsqrtf(var + 1e-5f);
#pragma unroll
        for (int j = 0; j < 4; ++j) {
            const int col = w * 64 + j * 16 + l16;
            const float val = (acc[j][reg] - mu) * rstd * g[col] + bta[col];
            Cs[r * 260 + col] = f2bf(val);
        }
    }
    __syncthreads();

    // Stage 2: dec[16,512]; wave w owns cols w*128..+127. A from LDS, B from L2.
    bf16x8 a2[8];
#pragma unroll
    for (int kk = 0; kk < 8; ++kk)
        a2[kk] = *(const bf16x8*)&Cs[l16 * 260 + kk * 32 + quad * 8];

#pragma unroll
    for (int j = 0; j < 8; ++j) {
        f32x4 acc2 = (f32x4){0.f, 0.f, 0.f, 0.f};
        const unsigned short* Bg = We + (size_t)(w * 128 + j * 16 + l16) * DC + quad * 8;
#pragma unroll
        for (int kk = 0; kk < 8; ++kk) {
            const bf16x8 b2 = *(const bf16x8*)(Bg + kk * 32);
            acc2 = __builtin_amdgcn_mfma_f32_16x16x32_bf16(a2[kk], b2, acc2, 0, 0, 0);
        }
        const int col = w * 128 + j * 16 + l16;
#pragma unroll
        for (int reg = 0; reg < 4; ++reg)
            dec[(size_t)(m0 + quad * 4 + reg) * DL + col] = f2bf(acc2[reg]);
    }
}

// ---------------------------------------------------------------------------
// MFMA flash attention (v3 mapping + truncation P-store + Ps stride 68).
// 1024 blocks = 32 heads x 32 q-tiles of 64 rows, LPT order; 4 waves of
// 16 q-rows. [round 6/7 lesson: occupancy > LDS volume here — 2-wave and
// 128-row restructures both regressed. Do not restructure.]
// Ps stride 68: quad row-offset = 8 banks mod 32 -> P b16 writes hit 32
// distinct banks (was 4-way colliding at stride 72).
// ---------------------------------------------------------------------------
__global__ __launch_bounds__(256, 3) void flash_mfma(
    const unsigned short* __restrict__ q, const unsigned short* __restrict__ k,
    const unsigned short* __restrict__ vt, unsigned short* __restrict__ o)
{
    __shared__ unsigned short Ks[64 * 72];
    __shared__ unsigned short Vs[64 * 72];
    __shared__ unsigned short Ps[64 * PSTR];

    const int bh = blockIdx.x & 31;
    const int j  = 31 - (blockIdx.x >> 5);     // LPT: heaviest first
    const int q0 = j * 64;
    const int tid = threadIdx.x;
    const int w = tid >> 6, lane = tid & 63;
    const int l16 = lane & 15, quad = lane >> 4;
    const int rbase = q0 + w * 16;

    bf16x8 qf[2];
#pragma unroll
    for (int kk = 0; kk < 2; ++kk)
        qf[kk] = *(const bf16x8*)(q + ((size_t)bh * T_SEQ + rbase + l16) * HDIM + kk * 32 + quad * 8);

    f32x4 of[4];
    float lrow[4];
#pragma unroll
    for (int dt = 0; dt < 4; ++dt) of[dt] = (f32x4){0.f, 0.f, 0.f, 0.f};
#pragma unroll
    for (int r = 0; r < 4; ++r) lrow[r] = 0.f;

    const int ldr = tid >> 2;
    const int ldc = (tid & 3) * 16;
    const unsigned short* kgb = k + ((size_t)bh * T_SEQ + ldr) * HDIM + ldc;
    const unsigned short* vgb = vt + ((size_t)bh * HDIM + ldr) * T_SEQ + ldc;

    const int kend = (j + 1) * 64;
    for (int k0 = 0; k0 < kend; k0 += 64) {
        __syncthreads();
        {
            const unsigned short* kg = kgb + (size_t)k0 * HDIM;
            *(bf16x8*)&Ks[ldr * 72 + ldc]     = *(const bf16x8*)kg;
            *(bf16x8*)&Ks[ldr * 72 + ldc + 8] = *(const bf16x8*)(kg + 8);
            const unsigned short* vg = vgb + k0;
            *(bf16x8*)&Vs[ldr * 72 + ldc]     = *(const bf16x8*)vg;
            *(bf16x8*)&Vs[ldr * 72 + ldc + 8] = *(const bf16x8*)(vg + 8);
        }
        __syncthreads();

        bf16x8 kf[4][2];
#pragma unroll
        for (int nt = 0; nt < 4; ++nt)
#pragma unroll
            for (int kk = 0; kk < 2; ++kk)
                kf[nt][kk] = *(const bf16x8*)&Ks[(nt * 16 + l16) * 72 + kk * 32 + quad * 8];

        f32x4 sf[4];
#pragma unroll
        for (int nt = 0; nt < 4; ++nt) {
            sf[nt] = (f32x4){0.f, 0.f, 0.f, 0.f};
#pragma unroll
            for (int kk = 0; kk < 2; ++kk)
                sf[nt] = __builtin_amdgcn_mfma_f32_16x16x32_bf16(qf[kk], kf[nt][kk], sf[nt], 0, 0, 0);
        }

        const bool need_mask = (k0 + 63) > rbase;
#pragma unroll
        for (int reg = 0; reg < 4; ++reg) {
            float a0 = sf[0][reg], a1 = sf[1][reg], a2 = sf[2][reg], a3 = sf[3][reg];
            if (need_mask) {
                const int tq = rbase + quad * 4 + reg;
                if (k0 +      l16 > tq) a0 = -1e30f;
                if (k0 + 16 + l16 > tq) a1 = -1e30f;
                if (k0 + 32 + l16 > tq) a2 = -1e30f;
                if (k0 + 48 + l16 > tq) a3 = -1e30f;
            }
            union { float f; unsigned u; } u0, u1, u2, u3;
            u0.f = exp2f(a0); u1.f = exp2f(a1);
            u2.f = exp2f(a2); u3.f = exp2f(a3);
            const int prow = (w * 16 + quad * 4 + reg) * PSTR + l16;
            Ps[prow]      = (unsigned short)(u0.u >> 16);
            Ps[prow + 16] = (unsigned short)(u1.u >> 16);
            Ps[prow + 32] = (unsigned short)(u2.u >> 16);
            Ps[prow + 48] = (unsigned short)(u3.u >> 16);
            u0.u &= 0xffff0000u; u1.u &= 0xffff0000u;
            u2.u &= 0xffff0000u; u3.u &= 0xffff0000u;
            lrow[reg] += (u0.f + u1.f) + (u2.f + u3.f);
        }

        bf16x8 vf[4][2];
#pragma unroll
        for (int dt = 0; dt < 4; ++dt)
#pragma unroll
            for (int kk = 0; kk < 2; ++kk)
                vf[dt][kk] = *(const bf16x8*)&Vs[(dt * 16 + l16) * 72 + kk * 32 + quad * 8];

        bf16x8 pf[2];
#pragma unroll
        for (int kk = 0; kk < 2; ++kk)
            pf[kk] = *(const bf16x8*)&Ps[(w * 16 + l16) * PSTR + kk * 32 + quad * 8];
#pragma unroll
        for (int dt = 0; dt < 4; ++dt)
#pragma unroll
            for (int kk = 0; kk < 2; ++kk)
                of[dt] = __builtin_amdgcn_mfma_f32_16x16x32_bf16(pf[kk], vf[dt][kk], of[dt], 0, 0, 0);
    }

    const int b = bh >> 4, h = bh & 15;
#pragma unroll
    for (int reg = 0; reg < 4; ++reg) {
        float l = lrow[reg];
        l += __shfl_xor(l, 1);
        l += __shfl_xor(l, 2);
        l += __shfl_xor(l, 4);
        l += __shfl_xor(l, 8);
        const float inv = 1.0f / l;
        const int t = rbase + quad * 4 + reg;
#pragma unroll
        for (int dt = 0; dt < 4; ++dt)
            o[((size_t)b * T_SEQ + t) * (NH * HDIM) + h * HDIM + dt * 16 + l16] =
                f2bf(of[dt][reg] * inv);
    }
}

// ---------------------------------------------------------------------------
extern "C" void kernel_launch(void* const* d_in, const int* in_sizes, int n_in,
                              void* d_out, int out_size, void* d_ws, size_t ws_size,
                              hipStream_t stream)
{
    (void)in_sizes; (void)n_in; (void)out_size; (void)ws_size;

    const float* x        = (const float*)d_in[0];
    const float* W_q      = (const float*)d_in[1];
    const float* b_q      = (const float*)d_in[2];
    const float* W_kvl    = (const float*)d_in[3];
    const float* b_kvl    = (const float*)d_in[4];
    const float* ts_scale = (const float*)d_in[5];
    const float* ts_shift = (const float*)d_in[6];
    const float* W_comp   = (const float*)d_in[7];
    const float* W_exp    = (const float*)d_in[8];
    const float* ln_g     = (const float*)d_in[9];
    const float* ln_b     = (const float*)d_in[10];
    const float* W_fkv    = (const float*)d_in[11];
    const float* b_fkv    = (const float*)d_in[12];
    const float* W_out    = (const float*)d_in[13];
    const float* b_out    = (const float*)d_in[14];
    float* out = (float*)d_out;

    char* p = (char*)d_ws;
    unsigned short* xb     = (unsigned short*)p;             p += 8  * 1024 * 1024;
    unsigned short* wqh    = (unsigned short*)p;             p += 2  * 1024 * 1024;
    unsigned short* wkvlh  = (unsigned short*)p;             p += 1  * 1024 * 1024;
    unsigned short* wcomph = (unsigned short*)p;             p += 256 * 1024;
    unsigned short* wexph  = (unsigned short*)p;             p += 256 * 1024;
    unsigned short* wfkvh  = (unsigned short*)p;             p += 2  * 1024 * 1024;
    unsigned short* wouth  = (unsigned short*)p;             p += 2  * 1024 * 1024;
    unsigned short* qh     = (unsigned short*)p;             p += 8  * 1024 * 1024;
    unsigned short* kh     = (unsigned short*)p;             p += 8  * 1024 * 1024;
    unsigned short* vth    = (unsigned short*)p;             p += 8  * 1024 * 1024;
    unsigned short* xt     = (unsigned short*)p;             p += 4  * 1024 * 1024;
    unsigned short* dec    = (unsigned short*)p;             p += 4  * 1024 * 1024;
    unsigned short* ob     = (unsigned short*)p;             p += 8  * 1024 * 1024;
    float2*         tab    = (float2*)p;                     p += 512 * 1024;

    const dim3 blk(256);

    cvt_bf16<<<1024, blk, 0, stream>>>(x, W_q, W_kvl, W_comp, W_exp, W_fkv, W_out,
                                       xb, wqh, wkvlh, wcomph, wexph, wfkvh, wouth,
                                       tab);

    gemm_qxt<<<dim3(64, 24), blk, 0, stream>>>(
        xb, wqh, wkvlh, b_q, b_kvl, ts_scale, ts_shift, tab, qh, xt);

    gemm_cb<<<256, blk, 0, stream>>>(
        xt, wcomph, wexph, ln_g, ln_b, dec);

    gemm_kv<<<dim3(64, 32), blk, 0, stream>>>(
        dec, wfkvh, b_fkv, tab, kh, vth);

    flash_mfma<<<1024, blk, 0, stream>>>(qh, kh, vth, ob);

    gemm_out<<<dim3(64, 16), blk, 0, stream>>>(
        ob, wouth, b_out, out);
}

// Round 10
// 220.938 us; speedup vs baseline: 1.1317x; 1.1317x over previous
//
#include <hip/hip_runtime.h>
#include <math.h>

#define B_SZ   2
#define T_SEQ  2048
#define NH     16
#define HDIM   64
#define D_MOD  1024
#define DL     512
#define DC     256
#define MROWS  4096   // B*T

typedef __attribute__((ext_vector_type(8))) short bf16x8;
typedef __attribute__((ext_vector_type(4))) float f32x4;

#define SCALE_Q 0.18033688011112042f   // (1/sqrt(64)) * log2(e)

static __device__ __forceinline__ unsigned short f2bf(float f) {
    union { float f; unsigned u; } v; v.f = f;
    unsigned r = v.u + 0x7fffu + ((v.u >> 16) & 1u);   // RNE
    return (unsigned short)(r >> 16);
}

// async global->LDS, 16B per lane; lds base wave-uniform, lane i -> base+i*16.
static __device__ __forceinline__ void gl_lds16(const unsigned short* g,
                                                unsigned short* l) {
    __builtin_amdgcn_global_load_lds(
        (const __attribute__((address_space(1))) unsigned int*)g,
        (__attribute__((address_space(3))) unsigned int*)l, 16, 0, 0);
}

// ---------------------------------------------------------------------------
// Convert x + 6 weights fp32 -> bf16, and build RoPE table [T,32] (cos,sin).
// ---------------------------------------------------------------------------
__global__ __launch_bounds__(256) void cvt_bf16(
    const float* __restrict__ x,  const float* __restrict__ wq,
    const float* __restrict__ wkvl, const float* __restrict__ wcomp,
    const float* __restrict__ wexp, const float* __restrict__ wfkv,
    const float* __restrict__ wout,
    unsigned short* __restrict__ xb,  unsigned short* __restrict__ wqh,
    unsigned short* __restrict__ wkvlh, unsigned short* __restrict__ wcomph,
    unsigned short* __restrict__ wexph, unsigned short* __restrict__ wfkvh,
    unsigned short* __restrict__ wouth, float2* __restrict__ rope_tab)
{
    const int g = blockIdx.x * 256 + threadIdx.x;
    const int stride = gridDim.x * 256;
#define CVT_SEG(src, dst, n4)                                              \
    for (int i = g; i < (n4); i += stride) {                               \
        float4 v = ((const float4*)(src))[i];                              \
        unsigned short h[4] = {f2bf(v.x), f2bf(v.y), f2bf(v.z), f2bf(v.w)};\
        *(uint2*)((dst) + (size_t)i * 4) = *(uint2*)h;                     \
    }
    CVT_SEG(x, xb, 1048576)
    CVT_SEG(wq, wqh, 262144)
    CVT_SEG(wkvl, wkvlh, 131072)
    CVT_SEG(wcomp, wcomph, 32768)
    CVT_SEG(wexp, wexph, 32768)
    CVT_SEG(wfkv, wfkvh, 262144)
    CVT_SEG(wout, wouth, 262144)
#undef CVT_SEG
    for (int i = g; i < T_SEQ * 32; i += stride) {
        const int t = i >> 5, fi = i & 31;
        const float inv = __expf((float)fi * (-9.210340371976184f / 32.0f));
        float sn, cs; sincosf((float)t * inv, &sn, &cs);
        rope_tab[i] = make_float2(cs, sn);
    }
}

// ===========================================================================
// 64x64-tile bf16 MFMA GEMM, BK=64, XOR-swizzled LDS (stride 64, no pad —
// gl_lds16-compatible). Lane i stages source col-group (i&7)^(i>>3); the
// fragment read of logical group (4kk+quad) at row r reads physical group
// (4kk+quad)^(r&7) -> uniform 8 accesses/bank (the old stride-32 layout hit
// only 16 of 32 banks = 2x LDS-read cycles). Barriers per K halved vs BK=32.
// Wave w owns rows w*16..w*16+15 x all 64 cols (RoPE col^32 stays in-wave).
// ===========================================================================
#define GEMM64R_PROLOG(Aptr, Wptr, Kdim)                                       \
    __shared__ unsigned short As[64 * 64];                                     \
    __shared__ unsigned short Ws[64 * 64];                                     \
    const int tid = threadIdx.x;                                               \
    const int w = tid >> 6, lane = tid & 63;                                   \
    const int l16 = lane & 15, quad = lane >> 4;                               \
    const int sw8 = ((lane & 7) ^ ((lane >> 3) & 7)) << 3;                     \
    const int srow = lane >> 3;                                                \
    const unsigned short* Ag0 = (Aptr) + (size_t)(m0 + w * 16 + srow) * (Kdim) + sw8;      \
    const unsigned short* Ag1 = (Aptr) + (size_t)(m0 + w * 16 + 8 + srow) * (Kdim) + sw8;  \
    const unsigned short* Wg0 = (Wptr) + (size_t)(n0 + w * 16 + srow) * (Kdim) + sw8;      \
    const unsigned short* Wg1 = (Wptr) + (size_t)(n0 + w * 16 + 8 + srow) * (Kdim) + sw8;  \
    unsigned short* Al0 = &As[(w * 16) * 64];                                  \
    unsigned short* Al1 = &As[(w * 16 + 8) * 64];                              \
    unsigned short* Wl0 = &Ws[(w * 16) * 64];                                  \
    unsigned short* Wl1 = &Ws[(w * 16 + 8) * 64];                              \
    const int xh = (l16 & 7);                                                  \
    f32x4 acc[4];                                                              \
    _Pragma("unroll") for (int j = 0; j < 4; ++j)                              \
        acc[j] = (f32x4){0.f, 0.f, 0.f, 0.f};                                  \
    for (int k0 = 0; k0 < (Kdim); k0 += 64) {                                  \
        __syncthreads();                                                       \
        gl_lds16(Ag0 + k0, Al0);                                               \
        gl_lds16(Ag1 + k0, Al1);                                               \
        gl_lds16(Wg0 + k0, Wl0);                                               \
        gl_lds16(Wg1 + k0, Wl1);                                               \
        __syncthreads();                                                       \
        bf16x8 af[2], bfr[4][2];                                               \
        _Pragma("unroll") for (int kk = 0; kk < 2; ++kk)                       \
            af[kk] = *(const bf16x8*)&As[(w * 16 + l16) * 64 +                 \
                                         (((kk * 4 + quad) ^ xh) << 3)];       \
        _Pragma("unroll") for (int j = 0; j < 4; ++j)                          \
            _Pragma("unroll") for (int kk = 0; kk < 2; ++kk)                   \
                bfr[j][kk] = *(const bf16x8*)&Ws[(j * 16 + l16) * 64 +         \
                                             (((kk * 4 + quad) ^ xh) << 3)];   \
        _Pragma("unroll") for (int kk = 0; kk < 2; ++kk)                       \
            _Pragma("unroll") for (int j = 0; j < 4; ++j)                      \
                acc[j] = __builtin_amdgcn_mfma_f32_16x16x32_bf16(              \
                    af[kk], bfr[j][kk], acc[j], 0, 0, 0);                      \
    }

// ---------------------------------------------------------------------------
// Combined Q-projection (+RoPE+scale) and XT (softplus) GEMM. grid (64, 24).
// ---------------------------------------------------------------------------
__global__ __launch_bounds__(256) void gemm_qxt(
    const unsigned short* __restrict__ A, const unsigned short* __restrict__ Wq,
    const unsigned short* __restrict__ Wkvl,
    const float* __restrict__ b_q, const float* __restrict__ b_kvl,
    const float* __restrict__ ts_scale, const float* __restrict__ ts_shift,
    const float2* __restrict__ tab,
    unsigned short* __restrict__ qh, unsigned short* __restrict__ xt)
{
    const int m0 = blockIdx.x * 64;
    const bool is_q = (blockIdx.y < 16);
    const int n0 = is_q ? blockIdx.y * 64 : (blockIdx.y - 16) * 64;
    const unsigned short* W = is_q ? Wq : Wkvl;

    GEMM64R_PROLOG(A, W, D_MOD)

    if (is_q) {
#pragma unroll
        for (int j = 0; j < 4; ++j) {
            const int col = n0 + j * 16 + l16;
            const int h = col >> 6, hd = col & 63;
            const float bv = b_q[col];
            const float bvp = b_q[col ^ 32];
            const float sgn = (hd < 32) ? -1.f : 1.f;
#pragma unroll
            for (int reg = 0; reg < 4; ++reg) {
                const int row = m0 + w * 16 + quad * 4 + reg;
                const int b = row >> 11, t = row & (T_SEQ - 1);
                const float2 cssn = tab[t * 32 + (hd & 31)];
                const float v  = acc[j][reg] + bv;
                const float vp = acc[j ^ 2][reg] + bvp;
                const float r = (v * cssn.x + sgn * vp * cssn.y) * SCALE_Q;
                qh[(((size_t)b * NH + h) * T_SEQ + t) * HDIM + hd] = f2bf(r);
            }
        }
    } else {
#pragma unroll
        for (int j = 0; j < 4; ++j) {
            const int col = n0 + j * 16 + l16;
            const float bv = b_kvl[col];
            const float sp_s = log1pf(expf(ts_scale[col]));
            const float sp_t = ts_shift[col];
#pragma unroll
            for (int reg = 0; reg < 4; ++reg) {
                const int row = m0 + w * 16 + quad * 4 + reg;
                const float val = (acc[j][reg] + bv) * sp_s + sp_t;
                xt[(size_t)row * DL + col] = f2bf(val);
            }
        }
    }
}

// ---------------------------------------------------------------------------
// KV decompress GEMM with fused K-RoPE and V-transpose. grid (64, 32).
// ---------------------------------------------------------------------------
__global__ __launch_bounds__(256) void gemm_kv(
    const unsigned short* __restrict__ A, const unsigned short* __restrict__ W,
    const float* __restrict__ bias, const float2* __restrict__ tab,
    unsigned short* __restrict__ kh, unsigned short* __restrict__ vth)
{
    const int m0 = blockIdx.x * 64, n0 = blockIdx.y * 64;

    GEMM64R_PROLOG(A, W, DL)

    if (n0 < 1024) {
        // K path: bias + RoPE -> kh [B*H, T, 64]
#pragma unroll
        for (int j = 0; j < 4; ++j) {
            const int col = n0 + j * 16 + l16;
            const int h = (col >> 6) & 15, hd = col & 63;
            const float bv = bias[col];
            const float bvp = bias[col ^ 32];
            const float sgn = (hd < 32) ? -1.f : 1.f;
#pragma unroll
            for (int reg = 0; reg < 4; ++reg) {
                const int row = m0 + w * 16 + quad * 4 + reg;
                const int b = row >> 11, t = row & (T_SEQ - 1);
                const float2 cssn = tab[t * 32 + (hd & 31)];
                const float v  = acc[j][reg] + bv;
                const float vp = acc[j ^ 2][reg] + bvp;
                const float r = v * cssn.x + sgn * vp * cssn.y;
                kh[(((size_t)b * NH + h) * T_SEQ + t) * HDIM + hd] = f2bf(r);
            }
        }
    } else {
        // V path: bias, transpose -> vth [B*H, 64, T] (packed 8B stores).
#pragma unroll
        for (int j = 0; j < 4; ++j) {
            const int col = n0 + j * 16 + l16;
            const int cv = col - 1024;
            const int h = cv >> 6, hd = cv & 63;
            const float bv = bias[col];
            unsigned short hv[4];
            const int r0 = m0 + w * 16 + quad * 4;
            const int b = r0 >> 11, t0 = r0 & (T_SEQ - 1);
#pragma unroll
            for (int reg = 0; reg < 4; ++reg)
                hv[reg] = f2bf(acc[j][reg] + bv);
            *(uint2*)&vth[(((size_t)b * NH + h) * HDIM + hd) * T_SEQ + t0] =
                *(uint2*)hv;
        }
    }
}

// ---------------------------------------------------------------------------
// Output GEMM: out[M,1024] fp32. grid (64, 16).
// ---------------------------------------------------------------------------
__global__ __launch_bounds__(256) void gemm_out(
    const unsigned short* __restrict__ A, const unsigned short* __restrict__ W,
    const float* __restrict__ bias, float* __restrict__ C)
{
    const int m0 = blockIdx.x * 64, n0 = blockIdx.y * 64;

    GEMM64R_PROLOG(A, W, D_MOD)

#pragma unroll
    for (int j = 0; j < 4; ++j) {
        const int col = n0 + j * 16 + l16;
        const float bv = bias[col];
#pragma unroll
        for (int reg = 0; reg < 4; ++reg) {
            const int row = m0 + w * 16 + quad * 4 + reg;
            C[(size_t)row * D_MOD + col] = acc[j][reg] + bv;
        }
    }
}

// ---------------------------------------------------------------------------
// B GEMM: dec[M,512] = cbh @ W_exp^T. grid (64, 8), K=256 (4 BK=64 iters).
// ---------------------------------------------------------------------------
__global__ __launch_bounds__(256) void gemm_b(
    const unsigned short* __restrict__ A, const unsigned short* __restrict__ W,
    unsigned short* __restrict__ dec)
{
    const int m0 = blockIdx.x * 64, n0 = blockIdx.y * 64;

    GEMM64R_PROLOG(A, W, DC)

#pragma unroll
    for (int j = 0; j < 4; ++j) {
        const int col = n0 + j * 16 + l16;
#pragma unroll
        for (int reg = 0; reg < 4; ++reg) {
            const int row = m0 + w * 16 + quad * 4 + reg;
            dec[(size_t)row * DL + col] = f2bf(acc[j][reg]);
        }
    }
}

// ---------------------------------------------------------------------------
// C-GEMM with fused LayerNorm (round-8 version). Block = 16 rows x 256 cols.
// One-pass var (E[x^2]-mu^2; no cancellation here). Grid: 256 blocks.
// ---------------------------------------------------------------------------
__global__ __launch_bounds__(256) void gemm_c_ln(
    const unsigned short* __restrict__ A, const unsigned short* __restrict__ W,
    const float* __restrict__ g, const float* __restrict__ bta,
    unsigned short* __restrict__ outb)
{
    __shared__ unsigned short As[16 * 32];
    __shared__ unsigned short Ws[256 * 32];
    __shared__ float redS[4][16];
    __shared__ float redQ[4][16];

    const int tid = threadIdx.x;
    const int w = tid >> 6, lane = tid & 63;
    const int l16 = lane & 15, quad = lane >> 4;
    const int m0 = blockIdx.x * 16;

    const int srow = lane >> 2, scol = (lane & 3) << 3;
    const unsigned short* Ag = A + (size_t)(m0 + srow) * DL + scol;
    const unsigned short* Wg = W + (size_t)(w * 64 + srow) * DL + scol;

    f32x4 acc[4];
#pragma unroll
    for (int j = 0; j < 4; ++j) acc[j] = (f32x4){0.f, 0.f, 0.f, 0.f};

    for (int k0 = 0; k0 < DL; k0 += 32) {
        __syncthreads();
        if (w == 0) gl_lds16(Ag + k0, &As[0]);
#pragma unroll
        for (int c = 0; c < 4; ++c)
            gl_lds16(Wg + (size_t)(c * 16) * DL + k0, &Ws[(w * 64 + c * 16) * 32]);
        __syncthreads();

        const bf16x8 af = *(const bf16x8*)&As[l16 * 32 + quad * 8];
        bf16x8 bfr[4];
#pragma unroll
        for (int j = 0; j < 4; ++j)
            bfr[j] = *(const bf16x8*)&Ws[(w * 64 + j * 16 + l16) * 32 + quad * 8];
#pragma unroll
        for (int j = 0; j < 4; ++j)
            acc[j] = __builtin_amdgcn_mfma_f32_16x16x32_bf16(af, bfr[j], acc[j], 0, 0, 0);
    }

    float s[4], q2[4];
#pragma unroll
    for (int reg = 0; reg < 4; ++reg) {
        float sv = (acc[0][reg] + acc[1][reg]) + (acc[2][reg] + acc[3][reg]);
        float qv = (acc[0][reg] * acc[0][reg] + acc[1][reg] * acc[1][reg]) +
                   (acc[2][reg] * acc[2][reg] + acc[3][reg] * acc[3][reg]);
#pragma unroll
        for (int off = 1; off < 16; off <<= 1) {
            sv += __shfl_xor(sv, off);
            qv += __shfl_xor(qv, off);
        }
        s[reg] = sv; q2[reg] = qv;
    }
    if (l16 == 0) {
#pragma unroll
        for (int reg = 0; reg < 4; ++reg) {
            redS[w][quad * 4 + reg] = s[reg];
            redQ[w][quad * 4 + reg] = q2[reg];
        }
    }
    __syncthreads();

#pragma unroll
    for (int reg = 0; reg < 4; ++reg) {
        const int r = quad * 4 + reg;
        const float sum = (redS[0][r] + redS[1][r]) + (redS[2][r] + redS[3][r]);
        const float sq  = (redQ[0][r] + redQ[1][r]) + (redQ[2][r] + redQ[3][r]);
        const float mu  = sum * (1.0f / DC);
        const float var = sq * (1.0f / DC) - mu * mu;
        const float rstd = rsqrtf(var + 1e-5f);
#pragma unroll
        for (int j = 0; j < 4; ++j) {
            const int col = w * 64 + j * 16 + l16;
            const float val = (acc[j][reg] - mu) * rstd * g[col] + bta[col];
            outb[(size_t)(m0 + r) * DC + col] = f2bf(val);
        }
    }
}

// ---------------------------------------------------------------------------
// MFMA flash attention (round-8 exact: v3 mapping + truncation P-store,
// Ps stride 72). 1024 blocks = 32 heads x 32 q-tiles of 64 rows, LPT;
// 4 waves of 16 q-rows. [r6/r7: occupancy > LDS volume — don't restructure.
// r9: Ps stride 68 broke pf b128 alignment — keep 72.]
// ---------------------------------------------------------------------------
__global__ __launch_bounds__(256, 3) void flash_mfma(
    const unsigned short* __restrict__ q, const unsigned short* __restrict__ k,
    const unsigned short* __restrict__ vt, unsigned short* __restrict__ o)
{
    __shared__ unsigned short Ks[64 * 72];
    __shared__ unsigned short Vs[64 * 72];
    __shared__ unsigned short Ps[64 * 72];

    const int bh = blockIdx.x & 31;
    const int j  = 31 - (blockIdx.x >> 5);     // LPT: heaviest first
    const int q0 = j * 64;
    const int tid = threadIdx.x;
    const int w = tid >> 6, lane = tid & 63;
    const int l16 = lane & 15, quad = lane >> 4;
    const int rbase = q0 + w * 16;

    bf16x8 qf[2];
#pragma unroll
    for (int kk = 0; kk < 2; ++kk)
        qf[kk] = *(const bf16x8*)(q + ((size_t)bh * T_SEQ + rbase + l16) * HDIM + kk * 32 + quad * 8);

    f32x4 of[4];
    float lrow[4];
#pragma unroll
    for (int dt = 0; dt < 4; ++dt) of[dt] = (f32x4){0.f, 0.f, 0.f, 0.f};
#pragma unroll
    for (int r = 0; r < 4; ++r) lrow[r] = 0.f;

    const int ldr = tid >> 2;
    const int ldc = (tid & 3) * 16;
    const unsigned short* kgb = k + ((size_t)bh * T_SEQ + ldr) * HDIM + ldc;
    const unsigned short* vgb = vt + ((size_t)bh * HDIM + ldr) * T_SEQ + ldc;

    const int kend = (j + 1) * 64;
    for (int k0 = 0; k0 < kend; k0 += 64) {
        __syncthreads();
        {
            const unsigned short* kg = kgb + (size_t)k0 * HDIM;
            *(bf16x8*)&Ks[ldr * 72 + ldc]     = *(const bf16x8*)kg;
            *(bf16x8*)&Ks[ldr * 72 + ldc + 8] = *(const bf16x8*)(kg + 8);
            const unsigned short* vg = vgb + k0;
            *(bf16x8*)&Vs[ldr * 72 + ldc]     = *(const bf16x8*)vg;
            *(bf16x8*)&Vs[ldr * 72 + ldc + 8] = *(const bf16x8*)(vg + 8);
        }
        __syncthreads();

        bf16x8 kf[4][2];
#pragma unroll
        for (int nt = 0; nt < 4; ++nt)
#pragma unroll
            for (int kk = 0; kk < 2; ++kk)
                kf[nt][kk] = *(const bf16x8*)&Ks[(nt * 16 + l16) * 72 + kk * 32 + quad * 8];

        f32x4 sf[4];
#pragma unroll
        for (int nt = 0; nt < 4; ++nt) {
            sf[nt] = (f32x4){0.f, 0.f, 0.f, 0.f};
#pragma unroll
            for (int kk = 0; kk < 2; ++kk)
                sf[nt] = __builtin_amdgcn_mfma_f32_16x16x32_bf16(qf[kk], kf[nt][kk], sf[nt], 0, 0, 0);
        }

        const bool need_mask = (k0 + 63) > rbase;
#pragma unroll
        for (int reg = 0; reg < 4; ++reg) {
            float a0 = sf[0][reg], a1 = sf[1][reg], a2 = sf[2][reg], a3 = sf[3][reg];
            if (need_mask) {
                const int tq = rbase + quad * 4 + reg;
                if (k0 +      l16 > tq) a0 = -1e30f;
                if (k0 + 16 + l16 > tq) a1 = -1e30f;
                if (k0 + 32 + l16 > tq) a2 = -1e30f;
                if (k0 + 48 + l16 > tq) a3 = -1e30f;
            }
            union { float f; unsigned u; } u0, u1, u2, u3;
            u0.f = exp2f(a0); u1.f = exp2f(a1);
            u2.f = exp2f(a2); u3.f = exp2f(a3);
            const int prow = (w * 16 + quad * 4 + reg) * 72 + l16;
            Ps[prow]      = (unsigned short)(u0.u >> 16);
            Ps[prow + 16] = (unsigned short)(u1.u >> 16);
            Ps[prow + 32] = (unsigned short)(u2.u >> 16);
            Ps[prow + 48] = (unsigned short)(u3.u >> 16);
            u0.u &= 0xffff0000u; u1.u &= 0xffff0000u;
            u2.u &= 0xffff0000u; u3.u &= 0xffff0000u;
            lrow[reg] += (u0.f + u1.f) + (u2.f + u3.f);
        }

        bf16x8 vf[4][2];
#pragma unroll
        for (int dt = 0; dt < 4; ++dt)
#pragma unroll
            for (int kk = 0; kk < 2; ++kk)
                vf[dt][kk] = *(const bf16x8*)&Vs[(dt * 16 + l16) * 72 + kk * 32 + quad * 8];

        bf16x8 pf[2];
#pragma unroll
        for (int kk = 0; kk < 2; ++kk)
            pf[kk] = *(const bf16x8*)&Ps[(w * 16 + l16) * 72 + kk * 32 + quad * 8];
#pragma unroll
        for (int dt = 0; dt < 4; ++dt)
#pragma unroll
            for (int kk = 0; kk < 2; ++kk)
                of[dt] = __builtin_amdgcn_mfma_f32_16x16x32_bf16(pf[kk], vf[dt][kk], of[dt], 0, 0, 0);
    }

    const int b = bh >> 4, h = bh & 15;
#pragma unroll
    for (int reg = 0; reg < 4; ++reg) {
        float l = lrow[reg];
        l += __shfl_xor(l, 1);
        l += __shfl_xor(l, 2);
        l += __shfl_xor(l, 4);
        l += __shfl_xor(l, 8);
        const float inv = 1.0f / l;
        const int t = rbase + quad * 4 + reg;
#pragma unroll
        for (int dt = 0; dt < 4; ++dt)
            o[((size_t)b * T_SEQ + t) * (NH * HDIM) + h * HDIM + dt * 16 + l16] =
                f2bf(of[dt][reg] * inv);
    }
}

// ---------------------------------------------------------------------------
extern "C" void kernel_launch(void* const* d_in, const int* in_sizes, int n_in,
                              void* d_out, int out_size, void* d_ws, size_t ws_size,
                              hipStream_t stream)
{
    (void)in_sizes; (void)n_in; (void)out_size; (void)ws_size;

    const float* x        = (const float*)d_in[0];
    const float* W_q      = (const float*)d_in[1];
    const float* b_q      = (const float*)d_in[2];
    const float* W_kvl    = (const float*)d_in[3];
    const float* b_kvl    = (const float*)d_in[4];
    const float* ts_scale = (const float*)d_in[5];
    const float* ts_shift = (const float*)d_in[6];
    const float* W_comp   = (const float*)d_in[7];
    const float* W_exp    = (const float*)d_in[8];
    const float* ln_g     = (const float*)d_in[9];
    const float* ln_b     = (const float*)d_in[10];
    const float* W_fkv    = (const float*)d_in[11];
    const float* b_fkv    = (const float*)d_in[12];
    const float* W_out    = (const float*)d_in[13];
    const float* b_out    = (const float*)d_in[14];
    float* out = (float*)d_out;

    char* p = (char*)d_ws;
    unsigned short* xb     = (unsigned short*)p;             p += 8  * 1024 * 1024;
    unsigned short* wqh    = (unsigned short*)p;             p += 2  * 1024 * 1024;
    unsigned short* wkvlh  = (unsigned short*)p;             p += 1  * 1024 * 1024;
    unsigned short* wcomph = (unsigned short*)p;             p += 256 * 1024;
    unsigned short* wexph  = (unsigned short*)p;             p += 256 * 1024;
    unsigned short* wfkvh  = (unsigned short*)p;             p += 2  * 1024 * 1024;
    unsigned short* wouth  = (unsigned short*)p;             p += 2  * 1024 * 1024;
    unsigned short* qh     = (unsigned short*)p;             p += 8  * 1024 * 1024;
    unsigned short* kh     = (unsigned short*)p;             p += 8  * 1024 * 1024;
    unsigned short* vth    = (unsigned short*)p;             p += 8  * 1024 * 1024;
    unsigned short* xt     = (unsigned short*)p;             p += 4  * 1024 * 1024;
    unsigned short* cbh    = (unsigned short*)p;             p += 2  * 1024 * 1024;
    unsigned short* dec    = (unsigned short*)p;             p += 4  * 1024 * 1024;
    unsigned short* ob     = (unsigned short*)p;             p += 8  * 1024 * 1024;
    float2*         tab    = (float2*)p;                     p += 512 * 1024;

    const dim3 blk(256);

    cvt_bf16<<<1024, blk, 0, stream>>>(x, W_q, W_kvl, W_comp, W_exp, W_fkv, W_out,
                                       xb, wqh, wkvlh, wcomph, wexph, wfkvh, wouth,
                                       tab);

    gemm_qxt<<<dim3(64, 24), blk, 0, stream>>>(
        xb, wqh, wkvlh, b_q, b_kvl, ts_scale, ts_shift, tab, qh, xt);

    gemm_c_ln<<<256, blk, 0, stream>>>(
        xt, wcomph, ln_g, ln_b, cbh);

    gemm_b<<<dim3(64, 8), blk, 0, stream>>>(
        cbh, wexph, dec);

    gemm_kv<<<dim3(64, 32), blk, 0, stream>>>(
        dec, wfkvh, b_fkv, tab, kh, vth);

    flash_mfma<<<1024, blk, 0, stream>>>(qh, kh, vth, ob);

    gemm_out<<<dim3(64, 16), blk, 0, stream>>>(
        ob, wouth, b_out, out);
}